// Round 15
// baseline (538.447 us; speedup 1.0000x reference)
//
#include <hip/hip_runtime.h>
#include <math.h>

#define NCELL 121
#define NB 256
#define DMODEL 128
#define DFF 512
#define LNEPS 1e-5f
#define MAXDEG 8
#define ROWS (NB * NCELL)  // 30976

typedef __attribute__((ext_vector_type(8))) short short8;
typedef __attribute__((ext_vector_type(4))) float f32x4;

#define MFMA(a, b, c) __builtin_amdgcn_mfma_f32_16x16x32_bf16(a, b, c, 0, 0, 0)

__device__ __forceinline__ float warp_sum64(float x) {
#pragma unroll
  for (int m = 32; m >= 1; m >>= 1) x += __shfl_xor(x, m, 64);
  return x;
}
__device__ __forceinline__ unsigned short f2bf(float f) {
  union { float f; unsigned u; } v; v.f = f;
  unsigned r = v.u + 0x7fffu + ((v.u >> 16) & 1u);
  return (unsigned short)(r >> 16);
}
__device__ __forceinline__ unsigned pack2(float a, float b) {
  return (unsigned)f2bf(a) | ((unsigned)f2bf(b) << 16);
}
__device__ __forceinline__ float bf2f(short s) {
  union { unsigned u; float f; } v;
  v.u = ((unsigned)(unsigned short)s) << 16;
  return v.f;
}
// Branch-free erf, |err| <= 1.5e-7 (A&S 7.1.26)
__device__ __forceinline__ float erf_fast(float x) {
  const float ax = fabsf(x);
  const float t = 1.0f / (1.0f + 0.3275911f * ax);
  const float p = t * (0.254829592f +
                  t * (-0.284496736f +
                  t * (1.421413741f +
                  t * (-1.453152027f +
                  t * 1.061405429f))));
  const float r = 1.0f - p * __expf(-ax * ax);
  return copysignf(r, x);
}
__device__ __forceinline__ float gelu_fast(float x) {
  return 0.5f * x * (1.0f + erf_fast(x * 0.70710678118654752f));
}
// tanh-form GELU (validated r13/r14): |err| <= 1e-3, ~10 VALU ops
__device__ __forceinline__ float gelu_tanh(float x) {
  const float x2 = x * x;
  const float z2 = x * (1.5957691f + 0.07135481f * x2);  // 2*z
  const float e = __expf(z2);
  return x - x / (e + 1.0f);
}
__device__ __forceinline__ float lrelu(float x) { return x > 0.0f ? x : 0.2f * x; }

// fp32 [L][K][N] -> bf16 transposed [L][N][K]
__global__ void k_cvt(const float* __restrict__ src, short* __restrict__ dst,
                      int K, int N, int total) {
  const int i = blockIdx.x * 256 + threadIdx.x;
  if (i >= total) return;
  const int KN = K * N;
  const int layer = i / KN, rem = i % KN;
  const int n = rem / K, kk = rem % K;
  dst[i] = (short)f2bf(src[(size_t)layer * KN + (size_t)kk * N + n]);
}

// one wave per node; ballot+prefix keeps edge order deterministic
__global__ void k_adj(const int* __restrict__ ei, int E,
                      int* __restrict__ deg, int* __restrict__ nbr) {
  const int node = blockIdx.x * 4 + (threadIdx.x >> 6);
  const int l = threadIdx.x & 63;
  if (node >= NCELL) return;
  const int* srcp = ei;
  const int* dstp = ei + E;
  int d = 0;
  for (int e0 = 0; e0 < E; e0 += 64) {
    const int e = e0 + l;
    const bool hit = (e < E) && (dstp[e] == node);
    const unsigned long long mb = __ballot(hit);
    if (hit) {
      const int pos = d + __popcll(mb & ((1ULL << l) - 1ULL));
      if (pos < MAXDEG) nbr[node * MAXDEG + pos] = srcp[e];
    }
    d += __popcll(mb);
  }
  if (l == 0) deg[node] = (d < MAXDEG ? d : MAXDEG);
}

// h = gelu(LN(x @ encW + encb)) ; 64 rows/block, grid 484
__global__ __launch_bounds__(256) void k_enc(
    const float* __restrict__ x, const float* __restrict__ W,
    const float* __restrict__ bias, const float* __restrict__ g,
    const float* __restrict__ be, float* __restrict__ h) {
  const int tid = threadIdx.x, w = tid >> 6, l = tid & 63;
  const int r0 = blockIdx.x * 64;
  for (int k = 0; k < 16; k++) {
    const int gr = r0 + w * 16 + k;
    const float* xr = x + (size_t)gr * 6;
    const float x0 = xr[0], x1 = xr[1], x2 = xr[2];
    const float x3 = xr[3], x4 = xr[4], x5 = xr[5];
    const int d1 = l + 64;
    float v0 = bias[l] + x0 * W[l] + x1 * W[DMODEL + l] + x2 * W[2 * DMODEL + l]
             + x3 * W[3 * DMODEL + l] + x4 * W[4 * DMODEL + l] + x5 * W[5 * DMODEL + l];
    float v1 = bias[d1] + x0 * W[d1] + x1 * W[DMODEL + d1] + x2 * W[2 * DMODEL + d1]
             + x3 * W[3 * DMODEL + d1] + x4 * W[4 * DMODEL + d1] + x5 * W[5 * DMODEL + d1];
    const float mean = warp_sum64(v0 + v1) * (1.0f / 128.0f);
    const float e0 = v0 - mean, e1 = v1 - mean;
    const float var = warp_sum64(e0 * e0 + e1 * e1) * (1.0f / 128.0f);
    const float rs = rsqrtf(var + LNEPS);
    float* hp = h + (size_t)gr * DMODEL;
    hp[l] = gelu_fast(e0 * rs * g[l] + be[l]);
    hp[d1] = gelu_fast(e1 * rs * g[d1] + be[d1]);
  }
}

// GAT part A (flat): hh = LN1(h) @ Wg (bf16 out), plus per-row per-head
// scores es/ed. 64 rows/block, grid 484; wave w owns head w (cols w*32..+32).
__global__ __launch_bounds__(256, 2) void k_gat_a(
    const float* __restrict__ g1, const float* __restrict__ b1,
    const short* __restrict__ Wgt, const float* __restrict__ asrc,
    const float* __restrict__ adst, const float* __restrict__ h,
    short* __restrict__ hh, float* __restrict__ es, float* __restrict__ ed) {
  __shared__ short sHn[64 * DMODEL];  // 16 KB swizzled bf16
  const int tid = threadIdx.x, w = tid >> 6, l = tid & 63;
  const int lane16 = l & 15, q = l >> 4;
  const int r0 = blockIdx.x * 64;

  // LN1 -> sHn: 4 lanes per row, single pass
  {
    const int row = tid >> 2, sub = tid & 3;
    const float* hr = h + (size_t)(r0 + row) * DMODEL + sub * 32;
    float4 v[8];
#pragma unroll
    for (int i = 0; i < 8; i++) v[i] = ((const float4*)hr)[i];
    float s = 0.f, ss = 0.f;
#pragma unroll
    for (int i = 0; i < 8; i++) {
      s += (v[i].x + v[i].y) + (v[i].z + v[i].w);
      ss += v[i].x * v[i].x + v[i].y * v[i].y + v[i].z * v[i].z + v[i].w * v[i].w;
    }
    s += __shfl_xor(s, 1, 64);  s += __shfl_xor(s, 2, 64);
    ss += __shfl_xor(ss, 1, 64); ss += __shfl_xor(ss, 2, 64);
    const float mean = s * (1.0f / 128.0f);
    const float var = fmaxf(ss * (1.0f / 128.0f) - mean * mean, 0.0f);
    const float rs = rsqrtf(var + LNEPS);
    const float4* gp = (const float4*)(g1 + sub * 32);
    const float4* bp = (const float4*)(b1 + sub * 32);
    const int sw = (row & 7) << 3;
#pragma unroll
    for (int jj = 0; jj < 4; jj++) {
      const float4 ga = gp[jj * 2], gb = gp[jj * 2 + 1];
      const float4 ba = bp[jj * 2], bb = bp[jj * 2 + 1];
      const float4 va = v[jj * 2], vb = v[jj * 2 + 1];
      uint4 u;
      u.x = pack2((va.x - mean) * rs * ga.x + ba.x, (va.y - mean) * rs * ga.y + ba.y);
      u.y = pack2((va.z - mean) * rs * ga.z + ba.z, (va.w - mean) * rs * ga.w + ba.w);
      u.z = pack2((vb.x - mean) * rs * gb.x + bb.x, (vb.y - mean) * rs * gb.y + bb.y);
      u.w = pack2((vb.z - mean) * rs * gb.z + bb.z, (vb.w - mean) * rs * gb.w + bb.w);
      *(uint4*)&sHn[row * DMODEL + ((sub * 32 + jj * 8) ^ sw)] = u;
    }
  }
  __syncthreads();

  // GEMM: M=64 rows, wave w -> cols [w*32, w*32+32), K=128
  f32x4 acc[4][2];
#pragma unroll
  for (int m = 0; m < 4; m++)
#pragma unroll
    for (int n = 0; n < 2; n++) acc[m][n] = (f32x4){0.f, 0.f, 0.f, 0.f};
#pragma unroll
  for (int ks = 0; ks < 4; ks++) {
    short8 a[4];
#pragma unroll
    for (int m = 0; m < 4; m++) {
      const int row = m * 16 + lane16;
      a[m] = *(const short8*)&sHn[row * DMODEL + ((ks * 32 + q * 8) ^ ((row & 7) << 3))];
    }
#pragma unroll
    for (int n = 0; n < 2; n++) {
      const short8 b = *(const short8*)&Wgt[(size_t)(w * 32 + n * 16 + lane16) * DMODEL + ks * 32 + q * 8];
#pragma unroll
      for (int m = 0; m < 4; m++) acc[m][n] = MFMA(a[m], b, acc[m][n]);
    }
  }

  // epilogue: hh (bf16, row-major global) + head-w scores via 16-lane reduce
  const float as0 = asrc[w * 32 + lane16], as1 = asrc[w * 32 + 16 + lane16];
  const float ad0 = adst[w * 32 + lane16], ad1 = adst[w * 32 + 16 + lane16];
#pragma unroll
  for (int m = 0; m < 4; m++) {
#pragma unroll
    for (int n = 0; n < 2; n++) {
      const int col = w * 32 + n * 16 + lane16;
#pragma unroll
      for (int r = 0; r < 4; r++) {
        const int row = m * 16 + q * 4 + r;
        hh[(size_t)(r0 + row) * DMODEL + col] = (short)f2bf(acc[m][n][r]);
      }
    }
#pragma unroll
    for (int r = 0; r < 4; r++) {
      float ps = acc[m][0][r] * as0 + acc[m][1][r] * as1;
      float pd = acc[m][0][r] * ad0 + acc[m][1][r] * ad1;
#pragma unroll
      for (int msk = 1; msk < 16; msk <<= 1) {
        ps += __shfl_xor(ps, msk, 64);
        pd += __shfl_xor(pd, msk, 64);
      }
      if (lane16 == 0) {
        const int gr = r0 + m * 16 + q * 4 + r;
        es[gr * 4 + w] = ps;
        ed[gr * 4 + w] = pd;
      }
    }
  }
}

// GAT part B: neighbor softmax + aggregate + residual + LN2 (bf16 pre-swizzled
// for ffn). One wave per (batch,node); grid ROWS/4 = 7744 (divisible by 8).
// XCD-aware block swizzle: each XCD gets a contiguous chunk of tasks so its
// private L2 holds only that chunk's hh rows.
__global__ __launch_bounds__(256) void k_gat_b(
    const float* __restrict__ es, const float* __restrict__ ed,
    const short* __restrict__ hh, const int* __restrict__ deg,
    const int* __restrict__ nbr, const float* __restrict__ g2,
    const float* __restrict__ bln, float* __restrict__ h,
    short* __restrict__ hn2) {
  const int tid = threadIdx.x, w = tid >> 6, l = tid & 63;
  const int nchunk = (int)gridDim.x >> 3;                 // 968
  const int bid = (int)blockIdx.x;
  const int swz = (bid & 7) * nchunk + (bid >> 3);        // bijective (nwg%8==0)
  const int task = swz * 4 + w;                           // global row in [0, ROWS)
  const int b = task / NCELL;
  const int j = task - b * NCELL;
  const int base = b * NCELL;
  const int dg = deg[j];

  // ---- weight phase: lane owns (neighbor n, head hd) ----
  const int n_own = l >> 2, hd_own = l & 3;
  int gi_own = base;
  float e_val = -1e30f;
  if (n_own < dg) {
    gi_own = base + nbr[j * MAXDEG + n_own];
    e_val = lrelu(es[gi_own * 4 + hd_own] + ed[task * 4 + hd_own]);
  }
  float mx = e_val;
#pragma unroll
  for (int msk = 4; msk < 64; msk <<= 1) mx = fmaxf(mx, __shfl_xor(mx, msk, 64));
  float ex = (n_own < dg) ? __expf(e_val - mx) : 0.0f;
  float sm = ex;
#pragma unroll
  for (int msk = 4; msk < 64; msk <<= 1) sm += __shfl_xor(sm, msk, 64);
  const float wnorm = ex / (sm + 1e-10f);

  // ---- aggregation: broadcast weight + neighbor index ----
  const int h0 = l >> 5, h2 = h0 + 2;
  float a0 = 0.0f, a1 = 0.0f;
  for (int n = 0; n < dg; n++) {
    const int gi = __shfl(gi_own, n * 4, 64);
    const float w0 = __shfl(wnorm, n * 4 + h0, 64);
    const float w2 = __shfl(wnorm, n * 4 + h2, 64);
    a0 = fmaf(w0, bf2f(hh[(size_t)gi * DMODEL + l]), a0);
    a1 = fmaf(w2, bf2f(hh[(size_t)gi * DMODEL + 64 + l]), a1);
  }
  float* hp = h + (size_t)task * DMODEL;
  const float v0 = hp[l] + a0;
  const float v1 = hp[l + 64] + a1;
  hp[l] = v0;
  hp[l + 64] = v1;

  // LN2 -> hn2 (bf16, pre-swizzled so ffn can copy straight into LDS)
  const float mean = warp_sum64(v0 + v1) * (1.0f / 128.0f);
  const float e0 = v0 - mean, e1 = v1 - mean;
  const float var = warp_sum64(e0 * e0 + e1 * e1) * (1.0f / 128.0f);
  const float rs = rsqrtf(var + LNEPS);
  const int sw = (task & 7) << 3;
  hn2[(size_t)task * DMODEL + (l ^ sw)] = (short)f2bf(e0 * rs * g2[l] + bln[l]);
  hn2[(size_t)task * DMODEL + ((l + 64) ^ sw)] = (short)f2bf(e1 * rs * g2[l + 64] + bln[l + 64]);
}

// One layer FFN over flattened rows: h += gelu(hn2@W1+b1)@W2+b2
// (hn2 = LN2(h) precomputed by k_gat_b). 32 rows/block, grid 968,
// LDS 40 KB -> 4 blocks/CU.
__global__ __launch_bounds__(256, 4) void k_ffn(
    const short* __restrict__ hn2,
    const short* __restrict__ W1t, const float* __restrict__ bb1,
    const short* __restrict__ W2t, const float* __restrict__ bb2,
    float* __restrict__ h) {
  __shared__ short sHn[32 * DMODEL];  // 8 KB swizzled bf16
  __shared__ short sT[32 * DFF];      // 32 KB swizzled bf16
  const int tid = threadIdx.x, w = tid >> 6, l = tid & 63;
  const int lane16 = l & 15, q = l >> 4;
  const int r0 = blockIdx.x * 32;

  // prefetch residual h rows at kernel entry (latency hidden by FF1+FF2)
  float hres[2][2][4];
#pragma unroll
  for (int m = 0; m < 2; m++)
#pragma unroll
    for (int n = 0; n < 2; n++) {
      const int col = w * 32 + n * 16 + lane16;
#pragma unroll
      for (int r = 0; r < 4; r++) {
        const int row = m * 16 + q * 4 + r;
        hres[m][n][r] = h[(size_t)(r0 + row) * DMODEL + col];
      }
    }

  // stage pre-swizzled hn2 -> LDS (pure copy, 8 KB)
  {
    const short* src = hn2 + (size_t)r0 * DMODEL;
#pragma unroll
    for (int i = 0; i < 2; i++) {
      const int off = (tid + i * 256) * 8;
      *(short8*)&sHn[off] = *(const short8*)&src[off];
    }
  }
  __syncthreads();

  // FF1: wave w -> t cols [w*128, w*128+128), all 32 rows
  f32x4 acc[2][8];
#pragma unroll
  for (int m = 0; m < 2; m++)
#pragma unroll
    for (int n = 0; n < 8; n++) acc[m][n] = (f32x4){0.f, 0.f, 0.f, 0.f};
#pragma unroll
  for (int ks = 0; ks < 4; ks++) {
    short8 a[2];
#pragma unroll
    for (int m = 0; m < 2; m++) {
      const int row = m * 16 + lane16;
      a[m] = *(const short8*)&sHn[row * DMODEL + ((ks * 32 + q * 8) ^ ((row & 7) << 3))];
    }
#pragma unroll
    for (int n = 0; n < 8; n++) {
      const short8 b = *(const short8*)&W1t[(size_t)(w * 128 + n * 16 + lane16) * DMODEL + ks * 32 + q * 8];
#pragma unroll
      for (int m = 0; m < 2; m++) acc[m][n] = MFMA(a[m], b, acc[m][n]);
    }
  }
  // gelu -> sT
#pragma unroll
  for (int m = 0; m < 2; m++)
#pragma unroll
    for (int n = 0; n < 8; n++) {
      const int col = w * 128 + n * 16 + lane16;
      const float bb = bb1[col];
#pragma unroll
      for (int r = 0; r < 4; r++) {
        const int row = m * 16 + q * 4 + r;
        sT[row * DFF + (col ^ ((row & 7) << 3))] = (short)f2bf(gelu_tanh(acc[m][n][r] + bb));
      }
    }
  __syncthreads();

  // FF2: wave w -> out cols [w*32, w*32+32), K=512; even/odd-ks split
  // doubles independent MFMA chains (4 -> 8).
  f32x4 oa[2][2], ob[2][2];
#pragma unroll
  for (int m = 0; m < 2; m++)
#pragma unroll
    for (int n = 0; n < 2; n++) {
      oa[m][n] = (f32x4){0.f, 0.f, 0.f, 0.f};
      ob[m][n] = (f32x4){0.f, 0.f, 0.f, 0.f};
    }
#pragma unroll
  for (int ks = 0; ks < 16; ks += 2) {
    short8 a0[2], a1[2];
#pragma unroll
    for (int m = 0; m < 2; m++) {
      const int row = m * 16 + lane16;
      a0[m] = *(const short8*)&sT[row * DFF + ((ks * 32 + q * 8) ^ ((row & 7) << 3))];
      a1[m] = *(const short8*)&sT[row * DFF + (((ks + 1) * 32 + q * 8) ^ ((row & 7) << 3))];
    }
#pragma unroll
    for (int n = 0; n < 2; n++) {
      const short8 b0 = *(const short8*)&W2t[(size_t)(w * 32 + n * 16 + lane16) * DFF + ks * 32 + q * 8];
      const short8 b1 = *(const short8*)&W2t[(size_t)(w * 32 + n * 16 + lane16) * DFF + (ks + 1) * 32 + q * 8];
#pragma unroll
      for (int m = 0; m < 2; m++) {
        oa[m][n] = MFMA(a0[m], b0, oa[m][n]);
        ob[m][n] = MFMA(a1[m], b1, ob[m][n]);
      }
    }
  }
  // residual + write
#pragma unroll
  for (int m = 0; m < 2; m++)
#pragma unroll
    for (int n = 0; n < 2; n++) {
      const int col = w * 32 + n * 16 + lane16;
      const float bb = bb2[col];
#pragma unroll
      for (int r = 0; r < 4; r++) {
        const int row = m * 16 + q * 4 + r;
        h[(size_t)(r0 + row) * DMODEL + col] = oa[m][n][r] + ob[m][n][r] + bb + hres[m][n][r];
      }
    }
}

// final LN in place; 4 lanes/row, 64 rows/block, grid 484
__global__ __launch_bounds__(256) void k_final(
    const float* __restrict__ g, const float* __restrict__ be,
    float* __restrict__ h) {
  const int tid = threadIdx.x;
  const int row = tid >> 2, sub = tid & 3;
  const int gr = blockIdx.x * 64 + row;
  float* hr = h + (size_t)gr * DMODEL + sub * 32;
  float4 v[8];
#pragma unroll
  for (int i = 0; i < 8; i++) v[i] = ((const float4*)hr)[i];
  float s = 0.f, ss = 0.f;
#pragma unroll
  for (int i = 0; i < 8; i++) {
    s += (v[i].x + v[i].y) + (v[i].z + v[i].w);
    ss += v[i].x * v[i].x + v[i].y * v[i].y + v[i].z * v[i].z + v[i].w * v[i].w;
  }
  s += __shfl_xor(s, 1, 64);  s += __shfl_xor(s, 2, 64);
  ss += __shfl_xor(ss, 1, 64); ss += __shfl_xor(ss, 2, 64);
  const float mean = s * (1.0f / 128.0f);
  const float var = fmaxf(ss * (1.0f / 128.0f) - mean * mean, 0.0f);
  const float rs = rsqrtf(var + LNEPS);
  const float4* gp = (const float4*)(g + sub * 32);
  const float4* bp = (const float4*)(be + sub * 32);
#pragma unroll
  for (int i = 0; i < 8; i++) {
    const float4 gg = gp[i], bb = bp[i];
    float4 y;
    y.x = (v[i].x - mean) * rs * gg.x + bb.x;
    y.y = (v[i].y - mean) * rs * gg.y + bb.y;
    y.z = (v[i].z - mean) * rs * gg.z + bb.z;
    y.w = (v[i].w - mean) * rs * gg.w + bb.w;
    ((float4*)hr)[i] = y;
  }
}

extern "C" void kernel_launch(void* const* d_in, const int* in_sizes, int n_in,
                              void* d_out, int out_size, void* d_ws, size_t ws_size,
                              hipStream_t stream) {
  const float* x     = (const float*)d_in[0];
  const float* encW  = (const float*)d_in[1];
  const float* encb  = (const float*)d_in[2];
  const float* encg  = (const float*)d_in[3];
  const float* encbe = (const float*)d_in[4];
  const float* ln1g  = (const float*)d_in[5];
  const float* ln1b  = (const float*)d_in[6];
  const float* gatW  = (const float*)d_in[7];
  const float* a_src = (const float*)d_in[8];
  const float* a_dst = (const float*)d_in[9];
  const float* ln2g  = (const float*)d_in[10];
  const float* ln2b  = (const float*)d_in[11];
  const float* ffW1  = (const float*)d_in[12];
  const float* ffb1  = (const float*)d_in[13];
  const float* ffW2  = (const float*)d_in[14];
  const float* ffb2  = (const float*)d_in[15];
  const float* fng   = (const float*)d_in[16];
  const float* fnb   = (const float*)d_in[17];
  const int*   ei    = (const int*)d_in[18];
  const int E = in_sizes[18] / 2;

  float* h = (float*)d_out;
  char* ws = (char*)d_ws;
  int* nbr = (int*)ws;                                    // 968 ints
  int* deg = nbr + NCELL * MAXDEG;                        // 121 ints
  short* wgt = (short*)(ws + 4608);                       // 6*128*128 bf16
  short* w1t = wgt + 6 * DMODEL * DMODEL;                 // 6*512*128 bf16
  short* w2t = w1t + 6 * DFF * DMODEL;                    // 6*128*512 bf16
  short* hh  = w2t + 6 * DFF * DMODEL;                    // ROWS*128 bf16 (7.9 MB)
  short* hn2 = hh + (size_t)ROWS * DMODEL;                // ROWS*128 bf16 (7.9 MB)
  float* es  = (float*)(hn2 + (size_t)ROWS * DMODEL);     // ROWS*4 f32
  float* ed  = es + (size_t)ROWS * 4;                     // ROWS*4 f32

  k_cvt<<<dim3((6 * 16384 + 255) / 256), dim3(256), 0, stream>>>(gatW, wgt, 128, 128, 6 * 16384);
  k_cvt<<<dim3((6 * 65536 + 255) / 256), dim3(256), 0, stream>>>(ffW1, w1t, 128, 512, 6 * 65536);
  k_cvt<<<dim3((6 * 65536 + 255) / 256), dim3(256), 0, stream>>>(ffW2, w2t, 512, 128, 6 * 65536);
  k_adj<<<dim3((NCELL + 3) / 4), dim3(256), 0, stream>>>(ei, E, deg, nbr);

  k_enc<<<dim3(ROWS / 64), dim3(256), 0, stream>>>(x, encW, encb, encg, encbe, h);
  for (int lyr = 0; lyr < 6; lyr++) {
    k_gat_a<<<dim3(ROWS / 64), dim3(256), 0, stream>>>(
        ln1g + lyr * DMODEL, ln1b + lyr * DMODEL,
        wgt + lyr * DMODEL * DMODEL,
        a_src + lyr * DMODEL, a_dst + lyr * DMODEL,
        h, hh, es, ed);
    k_gat_b<<<dim3(ROWS / 4), dim3(256), 0, stream>>>(
        es, ed, hh, deg, nbr,
        ln2g + lyr * DMODEL, ln2b + lyr * DMODEL, h, hn2);
    k_ffn<<<dim3(ROWS / 32), dim3(256), 0, stream>>>(
        hn2,
        w1t + lyr * DFF * DMODEL, ffb1 + lyr * DFF,
        w2t + lyr * DFF * DMODEL, ffb2 + lyr * DMODEL,
        h);
  }
  k_final<<<dim3(ROWS / 64), dim3(256), 0, stream>>>(fng, fnb, h);
}

// Round 16
// 480.010 us; speedup vs baseline: 1.1217x; 1.1217x over previous
//
#include <hip/hip_runtime.h>
#include <math.h>

#define NCELL 121
#define NB 256
#define DMODEL 128
#define DFF 512
#define LNEPS 1e-5f
#define MAXDEG 8
#define ROWS (NB * NCELL)  // 30976

typedef __attribute__((ext_vector_type(8))) short short8;
typedef __attribute__((ext_vector_type(4))) float f32x4;

#define MFMA(a, b, c) __builtin_amdgcn_mfma_f32_16x16x32_bf16(a, b, c, 0, 0, 0)

__device__ __forceinline__ float warp_sum64(float x) {
#pragma unroll
  for (int m = 32; m >= 1; m >>= 1) x += __shfl_xor(x, m, 64);
  return x;
}
__device__ __forceinline__ unsigned short f2bf(float f) {
  union { float f; unsigned u; } v; v.f = f;
  unsigned r = v.u + 0x7fffu + ((v.u >> 16) & 1u);
  return (unsigned short)(r >> 16);
}
__device__ __forceinline__ unsigned pack2(float a, float b) {
  return (unsigned)f2bf(a) | ((unsigned)f2bf(b) << 16);
}
__device__ __forceinline__ float bf2f(short s) {
  union { unsigned u; float f; } v;
  v.u = ((unsigned)(unsigned short)s) << 16;
  return v.f;
}
// Branch-free erf, |err| <= 1.5e-7 (A&S 7.1.26)
__device__ __forceinline__ float erf_fast(float x) {
  const float ax = fabsf(x);
  const float t = 1.0f / (1.0f + 0.3275911f * ax);
  const float p = t * (0.254829592f +
                  t * (-0.284496736f +
                  t * (1.421413741f +
                  t * (-1.453152027f +
                  t * 1.061405429f))));
  const float r = 1.0f - p * __expf(-ax * ax);
  return copysignf(r, x);
}
__device__ __forceinline__ float gelu_fast(float x) {
  return 0.5f * x * (1.0f + erf_fast(x * 0.70710678118654752f));
}
// tanh-form GELU (validated r13/r14): |err| <= 1e-3, ~10 VALU ops
__device__ __forceinline__ float gelu_tanh(float x) {
  const float x2 = x * x;
  const float z2 = x * (1.5957691f + 0.07135481f * x2);  // 2*z
  const float e = __expf(z2);
  return x - x / (e + 1.0f);
}
__device__ __forceinline__ float lrelu(float x) { return x > 0.0f ? x : 0.2f * x; }

// fp32 [L][K][N] -> bf16 transposed [L][N][K]
__global__ void k_cvt(const float* __restrict__ src, short* __restrict__ dst,
                      int K, int N, int total) {
  const int i = blockIdx.x * 256 + threadIdx.x;
  if (i >= total) return;
  const int KN = K * N;
  const int layer = i / KN, rem = i % KN;
  const int n = rem / K, kk = rem % K;
  dst[i] = (short)f2bf(src[(size_t)layer * KN + (size_t)kk * N + n]);
}

// one wave per node; ballot+prefix keeps edge order deterministic
__global__ void k_adj(const int* __restrict__ ei, int E,
                      int* __restrict__ deg, int* __restrict__ nbr) {
  const int node = blockIdx.x * 4 + (threadIdx.x >> 6);
  const int l = threadIdx.x & 63;
  if (node >= NCELL) return;
  const int* srcp = ei;
  const int* dstp = ei + E;
  int d = 0;
  for (int e0 = 0; e0 < E; e0 += 64) {
    const int e = e0 + l;
    const bool hit = (e < E) && (dstp[e] == node);
    const unsigned long long mb = __ballot(hit);
    if (hit) {
      const int pos = d + __popcll(mb & ((1ULL << l) - 1ULL));
      if (pos < MAXDEG) nbr[node * MAXDEG + pos] = srcp[e];
    }
    d += __popcll(mb);
  }
  if (l == 0) deg[node] = (d < MAXDEG ? d : MAXDEG);
}

// h = gelu(LN(x @ encW + encb)) ; 64 rows/block, grid 484
__global__ __launch_bounds__(256) void k_enc(
    const float* __restrict__ x, const float* __restrict__ W,
    const float* __restrict__ bias, const float* __restrict__ g,
    const float* __restrict__ be, float* __restrict__ h) {
  const int tid = threadIdx.x, w = tid >> 6, l = tid & 63;
  const int r0 = blockIdx.x * 64;
  for (int k = 0; k < 16; k++) {
    const int gr = r0 + w * 16 + k;
    const float* xr = x + (size_t)gr * 6;
    const float x0 = xr[0], x1 = xr[1], x2 = xr[2];
    const float x3 = xr[3], x4 = xr[4], x5 = xr[5];
    const int d1 = l + 64;
    float v0 = bias[l] + x0 * W[l] + x1 * W[DMODEL + l] + x2 * W[2 * DMODEL + l]
             + x3 * W[3 * DMODEL + l] + x4 * W[4 * DMODEL + l] + x5 * W[5 * DMODEL + l];
    float v1 = bias[d1] + x0 * W[d1] + x1 * W[DMODEL + d1] + x2 * W[2 * DMODEL + d1]
             + x3 * W[3 * DMODEL + d1] + x4 * W[4 * DMODEL + d1] + x5 * W[5 * DMODEL + d1];
    const float mean = warp_sum64(v0 + v1) * (1.0f / 128.0f);
    const float e0 = v0 - mean, e1 = v1 - mean;
    const float var = warp_sum64(e0 * e0 + e1 * e1) * (1.0f / 128.0f);
    const float rs = rsqrtf(var + LNEPS);
    float* hp = h + (size_t)gr * DMODEL;
    hp[l] = gelu_fast(e0 * rs * g[l] + be[l]);
    hp[d1] = gelu_fast(e1 * rs * g[d1] + be[d1]);
  }
}

// GAT part A (flat): hh = LN1(h) @ Wg (bf16 out), plus per-row per-head
// scores es/ed. 64 rows/block, grid 484; wave w owns head w (cols w*32..+32).
__global__ __launch_bounds__(256, 2) void k_gat_a(
    const float* __restrict__ g1, const float* __restrict__ b1,
    const short* __restrict__ Wgt, const float* __restrict__ asrc,
    const float* __restrict__ adst, const float* __restrict__ h,
    short* __restrict__ hh, float* __restrict__ es, float* __restrict__ ed) {
  __shared__ short sHn[64 * DMODEL];  // 16 KB swizzled bf16
  const int tid = threadIdx.x, w = tid >> 6, l = tid & 63;
  const int lane16 = l & 15, q = l >> 4;
  const int r0 = blockIdx.x * 64;

  // LN1 -> sHn: 4 lanes per row, single pass
  {
    const int row = tid >> 2, sub = tid & 3;
    const float* hr = h + (size_t)(r0 + row) * DMODEL + sub * 32;
    float4 v[8];
#pragma unroll
    for (int i = 0; i < 8; i++) v[i] = ((const float4*)hr)[i];
    float s = 0.f, ss = 0.f;
#pragma unroll
    for (int i = 0; i < 8; i++) {
      s += (v[i].x + v[i].y) + (v[i].z + v[i].w);
      ss += v[i].x * v[i].x + v[i].y * v[i].y + v[i].z * v[i].z + v[i].w * v[i].w;
    }
    s += __shfl_xor(s, 1, 64);  s += __shfl_xor(s, 2, 64);
    ss += __shfl_xor(ss, 1, 64); ss += __shfl_xor(ss, 2, 64);
    const float mean = s * (1.0f / 128.0f);
    const float var = fmaxf(ss * (1.0f / 128.0f) - mean * mean, 0.0f);
    const float rs = rsqrtf(var + LNEPS);
    const float4* gp = (const float4*)(g1 + sub * 32);
    const float4* bp = (const float4*)(b1 + sub * 32);
    const int sw = (row & 7) << 3;
#pragma unroll
    for (int jj = 0; jj < 4; jj++) {
      const float4 ga = gp[jj * 2], gb = gp[jj * 2 + 1];
      const float4 ba = bp[jj * 2], bb = bp[jj * 2 + 1];
      const float4 va = v[jj * 2], vb = v[jj * 2 + 1];
      uint4 u;
      u.x = pack2((va.x - mean) * rs * ga.x + ba.x, (va.y - mean) * rs * ga.y + ba.y);
      u.y = pack2((va.z - mean) * rs * ga.z + ba.z, (va.w - mean) * rs * ga.w + ba.w);
      u.z = pack2((vb.x - mean) * rs * gb.x + bb.x, (vb.y - mean) * rs * gb.y + bb.y);
      u.w = pack2((vb.z - mean) * rs * gb.z + bb.z, (vb.w - mean) * rs * gb.w + bb.w);
      *(uint4*)&sHn[row * DMODEL + ((sub * 32 + jj * 8) ^ sw)] = u;
    }
  }
  __syncthreads();

  // GEMM: M=64 rows, wave w -> cols [w*32, w*32+32), K=128
  f32x4 acc[4][2];
#pragma unroll
  for (int m = 0; m < 4; m++)
#pragma unroll
    for (int n = 0; n < 2; n++) acc[m][n] = (f32x4){0.f, 0.f, 0.f, 0.f};
#pragma unroll
  for (int ks = 0; ks < 4; ks++) {
    short8 a[4];
#pragma unroll
    for (int m = 0; m < 4; m++) {
      const int row = m * 16 + lane16;
      a[m] = *(const short8*)&sHn[row * DMODEL + ((ks * 32 + q * 8) ^ ((row & 7) << 3))];
    }
#pragma unroll
    for (int n = 0; n < 2; n++) {
      const short8 b = *(const short8*)&Wgt[(size_t)(w * 32 + n * 16 + lane16) * DMODEL + ks * 32 + q * 8];
#pragma unroll
      for (int m = 0; m < 4; m++) acc[m][n] = MFMA(a[m], b, acc[m][n]);
    }
  }

  // epilogue: hh (bf16, row-major global) + head-w scores via 16-lane reduce
  const float as0 = asrc[w * 32 + lane16], as1 = asrc[w * 32 + 16 + lane16];
  const float ad0 = adst[w * 32 + lane16], ad1 = adst[w * 32 + 16 + lane16];
#pragma unroll
  for (int m = 0; m < 4; m++) {
#pragma unroll
    for (int n = 0; n < 2; n++) {
      const int col = w * 32 + n * 16 + lane16;
#pragma unroll
      for (int r = 0; r < 4; r++) {
        const int row = m * 16 + q * 4 + r;
        hh[(size_t)(r0 + row) * DMODEL + col] = (short)f2bf(acc[m][n][r]);
      }
    }
#pragma unroll
    for (int r = 0; r < 4; r++) {
      float ps = acc[m][0][r] * as0 + acc[m][1][r] * as1;
      float pd = acc[m][0][r] * ad0 + acc[m][1][r] * ad1;
#pragma unroll
      for (int msk = 1; msk < 16; msk <<= 1) {
        ps += __shfl_xor(ps, msk, 64);
        pd += __shfl_xor(pd, msk, 64);
      }
      if (lane16 == 0) {
        const int gr = r0 + m * 16 + q * 4 + r;
        es[gr * 4 + w] = ps;
        ed[gr * 4 + w] = pd;
      }
    }
  }
}

// GAT part B: neighbor softmax + aggregate + residual + LN2 (bf16 pre-swizzled
// for ffn). One wave per (batch,node); grid ROWS/4.
__global__ __launch_bounds__(256) void k_gat_b(
    const float* __restrict__ es, const float* __restrict__ ed,
    const short* __restrict__ hh, const int* __restrict__ deg,
    const int* __restrict__ nbr, const float* __restrict__ g2,
    const float* __restrict__ bln, float* __restrict__ h,
    short* __restrict__ hn2) {
  const int tid = threadIdx.x, w = tid >> 6, l = tid & 63;
  const int task = blockIdx.x * 4 + w;          // global row in [0, ROWS)
  const int b = task / NCELL;
  const int j = task - b * NCELL;
  const int base = b * NCELL;
  const int dg = deg[j];

  // ---- weight phase: lane owns (neighbor n, head hd) ----
  const int n_own = l >> 2, hd_own = l & 3;
  int gi_own = base;
  float e_val = -1e30f;
  if (n_own < dg) {
    gi_own = base + nbr[j * MAXDEG + n_own];
    e_val = lrelu(es[gi_own * 4 + hd_own] + ed[task * 4 + hd_own]);
  }
  float mx = e_val;
#pragma unroll
  for (int msk = 4; msk < 64; msk <<= 1) mx = fmaxf(mx, __shfl_xor(mx, msk, 64));
  float ex = (n_own < dg) ? __expf(e_val - mx) : 0.0f;
  float sm = ex;
#pragma unroll
  for (int msk = 4; msk < 64; msk <<= 1) sm += __shfl_xor(sm, msk, 64);
  const float wnorm = ex / (sm + 1e-10f);

  // ---- aggregation: broadcast weight + neighbor index ----
  const int h0 = l >> 5, h2 = h0 + 2;
  float a0 = 0.0f, a1 = 0.0f;
  for (int n = 0; n < dg; n++) {
    const int gi = __shfl(gi_own, n * 4, 64);
    const float w0 = __shfl(wnorm, n * 4 + h0, 64);
    const float w2 = __shfl(wnorm, n * 4 + h2, 64);
    a0 = fmaf(w0, bf2f(hh[(size_t)gi * DMODEL + l]), a0);
    a1 = fmaf(w2, bf2f(hh[(size_t)gi * DMODEL + 64 + l]), a1);
  }
  float* hp = h + (size_t)task * DMODEL;
  const float v0 = hp[l] + a0;
  const float v1 = hp[l + 64] + a1;
  hp[l] = v0;
  hp[l + 64] = v1;

  // LN2 -> hn2 (bf16, pre-swizzled so ffn can copy straight into LDS)
  const float mean = warp_sum64(v0 + v1) * (1.0f / 128.0f);
  const float e0 = v0 - mean, e1 = v1 - mean;
  const float var = warp_sum64(e0 * e0 + e1 * e1) * (1.0f / 128.0f);
  const float rs = rsqrtf(var + LNEPS);
  const int sw = (task & 7) << 3;
  hn2[(size_t)task * DMODEL + (l ^ sw)] = (short)f2bf(e0 * rs * g2[l] + bln[l]);
  hn2[(size_t)task * DMODEL + ((l + 64) ^ sw)] = (short)f2bf(e1 * rs * g2[l + 64] + bln[l + 64]);
}

// One layer FFN over flattened rows: h += gelu(hn2@W1+b1)@W2+b2
// (hn2 = LN2(h) precomputed by k_gat_b). 32 rows/block, grid 968,
// LDS 40 KB -> 4 blocks/CU.
__global__ __launch_bounds__(256, 4) void k_ffn(
    const short* __restrict__ hn2,
    const short* __restrict__ W1t, const float* __restrict__ bb1,
    const short* __restrict__ W2t, const float* __restrict__ bb2,
    float* __restrict__ h) {
  __shared__ short sHn[32 * DMODEL];  // 8 KB swizzled bf16
  __shared__ short sT[32 * DFF];      // 32 KB swizzled bf16
  const int tid = threadIdx.x, w = tid >> 6, l = tid & 63;
  const int lane16 = l & 15, q = l >> 4;
  const int r0 = blockIdx.x * 32;

  // stage pre-swizzled hn2 -> LDS (pure copy, 8 KB)
  {
    const short* src = hn2 + (size_t)r0 * DMODEL;
#pragma unroll
    for (int i = 0; i < 2; i++) {
      const int off = (tid + i * 256) * 8;
      *(short8*)&sHn[off] = *(const short8*)&src[off];
    }
  }
  __syncthreads();

  // FF1: wave w -> t cols [w*128, w*128+128), all 32 rows
  f32x4 acc[2][8];
#pragma unroll
  for (int m = 0; m < 2; m++)
#pragma unroll
    for (int n = 0; n < 8; n++) acc[m][n] = (f32x4){0.f, 0.f, 0.f, 0.f};
#pragma unroll
  for (int ks = 0; ks < 4; ks++) {
    short8 a[2];
#pragma unroll
    for (int m = 0; m < 2; m++) {
      const int row = m * 16 + lane16;
      a[m] = *(const short8*)&sHn[row * DMODEL + ((ks * 32 + q * 8) ^ ((row & 7) << 3))];
    }
#pragma unroll
    for (int n = 0; n < 8; n++) {
      const short8 b = *(const short8*)&W1t[(size_t)(w * 128 + n * 16 + lane16) * DMODEL + ks * 32 + q * 8];
#pragma unroll
      for (int m = 0; m < 2; m++) acc[m][n] = MFMA(a[m], b, acc[m][n]);
    }
  }
  // gelu -> sT
#pragma unroll
  for (int m = 0; m < 2; m++)
#pragma unroll
    for (int n = 0; n < 8; n++) {
      const int col = w * 128 + n * 16 + lane16;
      const float bb = bb1[col];
#pragma unroll
      for (int r = 0; r < 4; r++) {
        const int row = m * 16 + q * 4 + r;
        sT[row * DFF + (col ^ ((row & 7) << 3))] = (short)f2bf(gelu_tanh(acc[m][n][r] + bb));
      }
    }
  __syncthreads();

  // prefetch residual h rows (issues before FF2's long loop)
  float hres[2][2][4];
#pragma unroll
  for (int m = 0; m < 2; m++)
#pragma unroll
    for (int n = 0; n < 2; n++) {
      const int col = w * 32 + n * 16 + lane16;
#pragma unroll
      for (int r = 0; r < 4; r++) {
        const int row = m * 16 + q * 4 + r;
        hres[m][n][r] = h[(size_t)(r0 + row) * DMODEL + col];
      }
    }

  // FF2: wave w -> out cols [w*32, w*32+32), K=512
  f32x4 o[2][2];
#pragma unroll
  for (int m = 0; m < 2; m++)
#pragma unroll
    for (int n = 0; n < 2; n++) o[m][n] = (f32x4){0.f, 0.f, 0.f, 0.f};
#pragma unroll
  for (int ks = 0; ks < 16; ks++) {
    short8 a[2];
#pragma unroll
    for (int m = 0; m < 2; m++) {
      const int row = m * 16 + lane16;
      a[m] = *(const short8*)&sT[row * DFF + ((ks * 32 + q * 8) ^ ((row & 7) << 3))];
    }
#pragma unroll
    for (int n = 0; n < 2; n++) {
      const short8 b = *(const short8*)&W2t[(size_t)(w * 32 + n * 16 + lane16) * DFF + ks * 32 + q * 8];
#pragma unroll
      for (int m = 0; m < 2; m++) o[m][n] = MFMA(a[m], b, o[m][n]);
    }
  }
  // residual + write
#pragma unroll
  for (int m = 0; m < 2; m++)
#pragma unroll
    for (int n = 0; n < 2; n++) {
      const int col = w * 32 + n * 16 + lane16;
      const float bb = bb2[col];
#pragma unroll
      for (int r = 0; r < 4; r++) {
        const int row = m * 16 + q * 4 + r;
        h[(size_t)(r0 + row) * DMODEL + col] = o[m][n][r] + bb + hres[m][n][r];
      }
    }
}

// final LN in place; 4 lanes/row, 64 rows/block, grid 484
__global__ __launch_bounds__(256) void k_final(
    const float* __restrict__ g, const float* __restrict__ be,
    float* __restrict__ h) {
  const int tid = threadIdx.x;
  const int row = tid >> 2, sub = tid & 3;
  const int gr = blockIdx.x * 64 + row;
  float* hr = h + (size_t)gr * DMODEL + sub * 32;
  float4 v[8];
#pragma unroll
  for (int i = 0; i < 8; i++) v[i] = ((const float4*)hr)[i];
  float s = 0.f, ss = 0.f;
#pragma unroll
  for (int i = 0; i < 8; i++) {
    s += (v[i].x + v[i].y) + (v[i].z + v[i].w);
    ss += v[i].x * v[i].x + v[i].y * v[i].y + v[i].z * v[i].z + v[i].w * v[i].w;
  }
  s += __shfl_xor(s, 1, 64);  s += __shfl_xor(s, 2, 64);
  ss += __shfl_xor(ss, 1, 64); ss += __shfl_xor(ss, 2, 64);
  const float mean = s * (1.0f / 128.0f);
  const float var = fmaxf(ss * (1.0f / 128.0f) - mean * mean, 0.0f);
  const float rs = rsqrtf(var + LNEPS);
  const float4* gp = (const float4*)(g + sub * 32);
  const float4* bp = (const float4*)(be + sub * 32);
#pragma unroll
  for (int i = 0; i < 8; i++) {
    const float4 gg = gp[i], bb = bp[i];
    float4 y;
    y.x = (v[i].x - mean) * rs * gg.x + bb.x;
    y.y = (v[i].y - mean) * rs * gg.y + bb.y;
    y.z = (v[i].z - mean) * rs * gg.z + bb.z;
    y.w = (v[i].w - mean) * rs * gg.w + bb.w;
    ((float4*)hr)[i] = y;
  }
}

extern "C" void kernel_launch(void* const* d_in, const int* in_sizes, int n_in,
                              void* d_out, int out_size, void* d_ws, size_t ws_size,
                              hipStream_t stream) {
  const float* x     = (const float*)d_in[0];
  const float* encW  = (const float*)d_in[1];
  const float* encb  = (const float*)d_in[2];
  const float* encg  = (const float*)d_in[3];
  const float* encbe = (const float*)d_in[4];
  const float* ln1g  = (const float*)d_in[5];
  const float* ln1b  = (const float*)d_in[6];
  const float* gatW  = (const float*)d_in[7];
  const float* a_src = (const float*)d_in[8];
  const float* a_dst = (const float*)d_in[9];
  const float* ln2g  = (const float*)d_in[10];
  const float* ln2b  = (const float*)d_in[11];
  const float* ffW1  = (const float*)d_in[12];
  const float* ffb1  = (const float*)d_in[13];
  const float* ffW2  = (const float*)d_in[14];
  const float* ffb2  = (const float*)d_in[15];
  const float* fng   = (const float*)d_in[16];
  const float* fnb   = (const float*)d_in[17];
  const int*   ei    = (const int*)d_in[18];
  const int E = in_sizes[18] / 2;

  float* h = (float*)d_out;
  char* ws = (char*)d_ws;
  int* nbr = (int*)ws;                                    // 968 ints
  int* deg = nbr + NCELL * MAXDEG;                        // 121 ints
  short* wgt = (short*)(ws + 4608);                       // 6*128*128 bf16
  short* w1t = wgt + 6 * DMODEL * DMODEL;                 // 6*512*128 bf16
  short* w2t = w1t + 6 * DFF * DMODEL;                    // 6*128*512 bf16
  short* hh  = w2t + 6 * DFF * DMODEL;                    // ROWS*128 bf16 (7.9 MB)
  short* hn2 = hh + (size_t)ROWS * DMODEL;                // ROWS*128 bf16 (7.9 MB)
  float* es  = (float*)(hn2 + (size_t)ROWS * DMODEL);     // ROWS*4 f32
  float* ed  = es + (size_t)ROWS * 4;                     // ROWS*4 f32

  k_cvt<<<dim3((6 * 16384 + 255) / 256), dim3(256), 0, stream>>>(gatW, wgt, 128, 128, 6 * 16384);
  k_cvt<<<dim3((6 * 65536 + 255) / 256), dim3(256), 0, stream>>>(ffW1, w1t, 128, 512, 6 * 65536);
  k_cvt<<<dim3((6 * 65536 + 255) / 256), dim3(256), 0, stream>>>(ffW2, w2t, 512, 128, 6 * 65536);
  k_adj<<<dim3((NCELL + 3) / 4), dim3(256), 0, stream>>>(ei, E, deg, nbr);

  k_enc<<<dim3(ROWS / 64), dim3(256), 0, stream>>>(x, encW, encb, encg, encbe, h);
  for (int lyr = 0; lyr < 6; lyr++) {
    k_gat_a<<<dim3(ROWS / 64), dim3(256), 0, stream>>>(
        ln1g + lyr * DMODEL, ln1b + lyr * DMODEL,
        wgt + lyr * DMODEL * DMODEL,
        a_src + lyr * DMODEL, a_dst + lyr * DMODEL,
        h, hh, es, ed);
    k_gat_b<<<dim3(ROWS / 4), dim3(256), 0, stream>>>(
        es, ed, hh, deg, nbr,
        ln2g + lyr * DMODEL, ln2b + lyr * DMODEL, h, hn2);
    k_ffn<<<dim3(ROWS / 32), dim3(256), 0, stream>>>(
        hn2,
        w1t + lyr * DFF * DMODEL, ffb1 + lyr * DFF,
        w2t + lyr * DFF * DMODEL, ffb2 + lyr * DMODEL,
        h);
  }
  k_final<<<dim3(ROWS / 64), dim3(256), 0, stream>>>(fng, fnb, h);
}